// Round 4
// baseline (428.462 us; speedup 1.0000x reference)
//
#include <hip/hip_runtime.h>

#define NN 512       // nodes
#define BB_ 64       // batch
#define EE 32768     // edges
#define TT 50        // input channels
#define FF 32        // hidden channels

// ws float offsets
#define OFF_LHAT 0
#define OFF_DEG  (512 * 512)
#define OFF_FC1O (OFF_DEG + 512)
#define OFF_H    (OFF_FC1O + BB_ * 256)
#define OFF_G    (OFF_H + NN * BB_ * FF)
#define OFF_F0   (OFF_G + NN * BB_ * FF)
#define WS_FLOATS (OFF_F0 + NN * BB_ * FF)

// ---------------- setup kernels ----------------

__global__ void k_zero_out(float* out, int n) {
    int i = blockIdx.x * blockDim.x + threadIdx.x;
    if (i < n) out[i] = 0.f;
}

__global__ void k_zero_range(float* p, int n) {
    int i = blockIdx.x * blockDim.x + threadIdx.x;
    if (i < n) p[i] = 0.f;
}

__global__ void k_deg(const int* __restrict__ ei, const float* __restrict__ ew,
                      float* __restrict__ deg) {
    int e = blockIdx.x * blockDim.x + threadIdx.x;
    if (e >= EE) return;
    int s = ei[e] & (NN - 1), d = ei[EE + e] & (NN - 1);
    if (s != d) atomicAdd(&deg[s], ew[e]);
}

__global__ void k_dinv(float* deg) {
    int i = threadIdx.x;   // 512 threads, 1 block
    float d = deg[i];
    deg[i] = (d > 0.f) ? rsqrtf(d) : 0.f;
}

// dense Lhat[d][s] += -(dinv[s] * w * dinv[d])
__global__ void k_build(const int* __restrict__ ei, const float* __restrict__ ew,
                        const float* __restrict__ dinv, float* __restrict__ Lhat) {
    int e = blockIdx.x * blockDim.x + threadIdx.x;
    if (e >= EE) return;
    int s = ei[e] & (NN - 1), d = ei[EE + e] & (NN - 1);
    if (s == d) return;
    float nm = -(dinv[s] * ew[e] * dinv[d]);
    atomicAdd(&Lhat[d * NN + s], nm);
}

// ---------------- small GEMM: G = H W1, F0 = H W0 + b ----------------
// rows r = n*64+b (node-major). grid 4096, block 256 = 8 rows x 32 f.
template<int CIN, bool FROM_X>
__global__ __launch_bounds__(256) void k_small(
        const float* __restrict__ Hin,   // FROM_X: x[b][n][CIN]; else node-major [r][CIN]
        const float* __restrict__ W,     // [2][CIN][32]
        const float* __restrict__ bias,
        float* __restrict__ G, float* __restrict__ F0) {
    __shared__ float W0s[CIN * FF];
    __shared__ float W1s[CIN * FF];
    __shared__ float bs[FF];
    __shared__ float rows[8][CIN];
    const int tid = threadIdx.x;
    for (int i = tid; i < CIN * FF; i += 256) {
        W0s[i] = W[i];
        W1s[i] = W[CIN * FF + i];
    }
    if (tid < FF) bs[tid] = bias[tid];
    const int g = tid >> 5, f = tid & 31;
    const int r = blockIdx.x * 8 + g;
    const int n = r >> 6, b = r & 63;
    const float* src = FROM_X ? (Hin + ((size_t)b * NN + n) * CIN)
                              : (Hin + (size_t)r * CIN);
    for (int t = f; t < CIN; t += 32) rows[g][t] = src[t];
    __syncthreads();
    float gacc = 0.f, facc = bs[f];
#pragma unroll 2
    for (int t = 0; t < CIN; ++t) {
        float hv = rows[g][t];
        gacc = fmaf(hv, W1s[t * FF + f], gacc);
        facc = fmaf(hv, W0s[t * FF + f], facc);
    }
    G [(size_t)r * FF + f] = gacc;
    F0[(size_t)r * FF + f] = facc;
}

// ---------------- big GEMM: H = [relu](Lhat @ G + F0) ----------------
// Lhat 512x512, G/F0/H 512x2048 (node-major). tile 64x64, thread 4x4.
// grid (2048/64=32, 512/64=8), block 256 (tx 0..15 cols, ty 0..15 rows).
template<bool RELU>
__global__ __launch_bounds__(256) void k_prop(
        const float* __restrict__ L, const float* __restrict__ G,
        const float* __restrict__ F0, float* __restrict__ H) {
    __shared__ float As[16][68];   // As[k][i] = L[i0+i][k0+k]
    __shared__ float Bs[16][68];   // Bs[k][j] = G[k0+k][j0+j]
    const int tid = threadIdx.x;
    const int tx = tid & 15, ty = tid >> 4;
    const int i0 = blockIdx.y * 64;
    const int j0 = blockIdx.x * 64;
    float acc[4][4] = {};
    const int ar = tid >> 2, ak = (tid & 3) * 4;     // A stage: row, k-col
    const int br = tid >> 4, bc = (tid & 15) * 4;    // B stage: k-row, col

    for (int k0 = 0; k0 < NN; k0 += 16) {
        const float4 av = *(const float4*)&L[(size_t)(i0 + ar) * NN + k0 + ak];
        const float4 bv = *(const float4*)&G[(size_t)(k0 + br) * (BB_ * FF) + j0 + bc];
        __syncthreads();
        As[ak + 0][ar] = av.x;
        As[ak + 1][ar] = av.y;
        As[ak + 2][ar] = av.z;
        As[ak + 3][ar] = av.w;
        *(float4*)&Bs[br][bc] = bv;
        __syncthreads();
#pragma unroll
        for (int k = 0; k < 16; ++k) {
            float a[4], b[4];
            *(float4*)a = *(const float4*)&As[k][ty * 4];
            *(float4*)b = *(const float4*)&Bs[k][tx * 4];
#pragma unroll
            for (int m = 0; m < 4; ++m)
#pragma unroll
                for (int nn2 = 0; nn2 < 4; ++nn2)
                    acc[m][nn2] = fmaf(a[m], b[nn2], acc[m][nn2]);
        }
    }
#pragma unroll
    for (int m = 0; m < 4; ++m) {
        const size_t row = i0 + ty * 4 + m;
        float4 f0 = *(const float4*)&F0[row * (BB_ * FF) + j0 + tx * 4];
        float4 o;
        o.x = acc[m][0] + f0.x; o.y = acc[m][1] + f0.y;
        o.z = acc[m][2] + f0.z; o.w = acc[m][3] + f0.w;
        if (RELU) {
            o.x = fmaxf(o.x, 0.f); o.y = fmaxf(o.y, 0.f);
            o.z = fmaxf(o.z, 0.f); o.w = fmaxf(o.w, 0.f);
        }
        *(float4*)&H[row * (BB_ * FF) + j0 + tx * 4] = o;
    }
}

// ---------------- FC1: out[b][j] = sum_{k} A[b][k] W[k][j] ----------------
// A[b][k] with k=n*32+f -> h[(k>>5)*2048 + b*32 + (k&31)] (node-major h)
// grid (64 col-tiles of 4, 8 K-splits of 2048); block 256.
__global__ __launch_bounds__(256) void k_fc1(const float* __restrict__ h,
                                             const float* __restrict__ W,
                                             float* __restrict__ out) {
    __shared__ float As[64][68];
    __shared__ float Ws[64][4];
    const int tid  = threadIdx.x;
    const int m    = tid >> 2;
    const int j4   = tid & 3;
    const int jcol = blockIdx.x * 4 + j4;
    const int kb   = blockIdx.y * 2048;
    float acc = 0.f;
    for (int kt = 0; kt < 32; ++kt) {
        const int k0 = kb + kt * 64;
        __syncthreads();
#pragma unroll
        for (int u = 0; u < 16; ++u) {
            int idx = tid + u * 256;
            int r = idx >> 6, c = idx & 63;
            int k = k0 + c;
            As[r][c] = h[(size_t)(k >> 5) * (BB_ * FF) + r * FF + (k & 31)];
        }
        Ws[tid >> 2][tid & 3] = W[(size_t)(k0 + (tid >> 2)) * 256 + blockIdx.x * 4 + (tid & 3)];
        __syncthreads();
#pragma unroll
        for (int kk = 0; kk < 64; ++kk)
            acc = fmaf(As[m][kk], Ws[kk][j4], acc);
    }
    atomicAdd(&out[m * 256 + jcol], acc);
}

// ---------------- fused FC2 + FC3 ----------------
__global__ __launch_bounds__(128) void k_fc23(const float* __restrict__ fc1o,
        const float* __restrict__ b1, const float* __restrict__ W2,
        const float* __restrict__ b2, const float* __restrict__ W3,
        const float* __restrict__ b3, float* __restrict__ out) {
    __shared__ float row[128];
    const int m = blockIdx.x, j = threadIdx.x;
    const float* a = fc1o + m * 256;
    float acc = b2[j];
    for (int k = 0; k < 256; ++k)
        acc = fmaf(a[k] + b1[k], W2[k * 128 + j], acc);
    row[j] = acc;
    __syncthreads();
    const int w = j >> 6, l = j & 63;
    float s = row[l] * W3[l * 2 + w] + row[l + 64] * W3[(l + 64) * 2 + w];
#pragma unroll
    for (int off = 32; off > 0; off >>= 1)
        s += __shfl_down(s, off);
    if (l == 0) out[m * 2 + w] = s + b3[w];
}

// ---------------- launch ----------------

extern "C" void kernel_launch(void* const* d_in, const int* in_sizes, int n_in,
                              void* d_out, int out_size, void* d_ws, size_t ws_size,
                              hipStream_t stream) {
    float* outp = (float*)d_out;
    if (ws_size < (size_t)WS_FLOATS * sizeof(float)) {
        k_zero_out<<<(out_size + 255) / 256, 256, 0, stream>>>(outp, out_size);
        return;
    }

    const float* x  = (const float*)d_in[0];
    const int*   ei = (const int*)d_in[1];     // int64 in ref -> int32 from harness
    const float* ew = (const float*)d_in[2];
    const float* cW[6] = {(const float*)d_in[3], (const float*)d_in[5],
                          (const float*)d_in[7], (const float*)d_in[9],
                          (const float*)d_in[11], (const float*)d_in[13]};
    const float* cb[6] = {(const float*)d_in[4], (const float*)d_in[6],
                          (const float*)d_in[8], (const float*)d_in[10],
                          (const float*)d_in[12], (const float*)d_in[14]};
    const float* fc1W = (const float*)d_in[15];
    const float* fc1b = (const float*)d_in[16];
    const float* fc2W = (const float*)d_in[17];
    const float* fc2b = (const float*)d_in[18];
    const float* fc3W = (const float*)d_in[19];
    const float* fc3b = (const float*)d_in[20];

    float* ws   = (float*)d_ws;
    float* Lhat = ws + OFF_LHAT;
    float* deg  = ws + OFF_DEG;
    float* fc1o = ws + OFF_FC1O;
    float* H    = ws + OFF_H;
    float* G    = ws + OFF_G;
    float* F0   = ws + OFF_F0;

    // build dense Lhat (also zeroes deg + fc1o, contiguous range)
    k_zero_range<<<(OFF_H + 255) / 256, 256, 0, stream>>>(ws, OFF_H);
    k_deg<<<EE / 256, 256, 0, stream>>>(ei, ew, deg);
    k_dinv<<<1, 512, 0, stream>>>(deg);
    k_build<<<EE / 256, 256, 0, stream>>>(ei, ew, deg, Lhat);

    dim3 pgrid(32, 8);
    const int sgrid = NN * BB_ / 8;

    // layer 1 (CIN=50, from x)
    k_small<TT, true ><<<sgrid, 256, 0, stream>>>(x, cW[0], cb[0], G, F0);
    k_prop<true ><<<pgrid, 256, 0, stream>>>(Lhat, G, F0, H);
    // layers 2..5
    k_small<FF, false><<<sgrid, 256, 0, stream>>>(H, cW[1], cb[1], G, F0);
    k_prop<true ><<<pgrid, 256, 0, stream>>>(Lhat, G, F0, H);
    k_small<FF, false><<<sgrid, 256, 0, stream>>>(H, cW[2], cb[2], G, F0);
    k_prop<true ><<<pgrid, 256, 0, stream>>>(Lhat, G, F0, H);
    k_small<FF, false><<<sgrid, 256, 0, stream>>>(H, cW[3], cb[3], G, F0);
    k_prop<true ><<<pgrid, 256, 0, stream>>>(Lhat, G, F0, H);
    k_small<FF, false><<<sgrid, 256, 0, stream>>>(H, cW[4], cb[4], G, F0);
    k_prop<true ><<<pgrid, 256, 0, stream>>>(Lhat, G, F0, H);
    // layer 6 (no relu)
    k_small<FF, false><<<sgrid, 256, 0, stream>>>(H, cW[5], cb[5], G, F0);
    k_prop<false><<<pgrid, 256, 0, stream>>>(Lhat, G, F0, H);

    // FC head
    dim3 fgrid(64, 8);
    k_fc1<<<fgrid, 256, 0, stream>>>(H, fc1W, fc1o);
    k_fc23<<<64, 128, 0, stream>>>(fc1o, fc1b, fc2W, fc2b, fc3W, fc3b, outp);
}

// Round 6
// 392.130 us; speedup vs baseline: 1.0927x; 1.0927x over previous
//
#include <hip/hip_runtime.h>

#define NN 512       // nodes
#define BB_ 64       // batch
#define EE 32768     // edges
#define TT 50        // input channels
#define FF 32        // hidden channels
#define NB 2048      // BB_*FF : width of node-major feature rows

// ws float offsets
#define OFF_LHAT 0
#define OFF_DEG  (512 * 512)
#define OFF_H    (OFF_DEG + 512)
#define OFF_G    (OFF_H + NN * NB)
#define OFF_F0   (OFF_G + NN * NB)
#define WS_FLOATS (OFF_F0 + NN * NB)
// P (fc1 partials, 128*64*256 = 2M floats = 8MB) aliases G+F0 (dead at fc1 time)

// ---------------- setup kernels ----------------

__global__ void k_zero_out(float* out, int n) {
    int i = blockIdx.x * blockDim.x + threadIdx.x;
    if (i < n) out[i] = 0.f;
}

__global__ void k_zero_range(float* p, int n) {
    int i = blockIdx.x * blockDim.x + threadIdx.x;
    if (i < n) p[i] = 0.f;
}

__global__ void k_deg(const int* __restrict__ ei, const float* __restrict__ ew,
                      float* __restrict__ deg) {
    int e = blockIdx.x * blockDim.x + threadIdx.x;
    if (e >= EE) return;
    int s = ei[e] & (NN - 1), d = ei[EE + e] & (NN - 1);
    if (s != d) atomicAdd(&deg[s], ew[e]);
}

__global__ void k_dinv(float* deg) {
    int i = threadIdx.x;
    float d = deg[i];
    deg[i] = (d > 0.f) ? rsqrtf(d) : 0.f;
}

__global__ void k_build(const int* __restrict__ ei, const float* __restrict__ ew,
                        const float* __restrict__ dinv, float* __restrict__ Lhat) {
    int e = blockIdx.x * blockDim.x + threadIdx.x;
    if (e >= EE) return;
    int s = ei[e] & (NN - 1), d = ei[EE + e] & (NN - 1);
    if (s == d) return;
    float nm = -(dinv[s] * ew[e] * dinv[d]);
    atomicAdd(&Lhat[d * NN + s], nm);
}

// ---------------- small GEMM: G = H W1, F0 = H W0 + b ----------------
// node-major rows r = n*64+b. 64 rows/block, grid 512, block 256 = 8 rowslots x 32 f.
template<int CIN, bool FROM_X>
__global__ __launch_bounds__(256) void k_small(
        const float* __restrict__ Hin, const float* __restrict__ W,
        const float* __restrict__ bias,
        float* __restrict__ G, float* __restrict__ F0) {
    __shared__ float W0s[CIN * FF];
    __shared__ float W1s[CIN * FF];
    __shared__ float bs[FF];
    __shared__ float rows[64][CIN];
    const int tid = threadIdx.x;
    for (int i = tid; i < CIN * FF; i += 256) {
        W0s[i] = W[i];
        W1s[i] = W[CIN * FF + i];
    }
    if (tid < FF) bs[tid] = bias[tid];
    const int r0 = blockIdx.x * 64;
    for (int idx = tid; idx < 64 * CIN; idx += 256) {
        int r = idx / CIN, c = idx % CIN;
        int R = r0 + r;
        rows[r][c] = FROM_X ? Hin[((size_t)(R & 63) * NN + (R >> 6)) * CIN + c]
                            : Hin[(size_t)R * CIN + c];
    }
    __syncthreads();
    const int f = tid & 31, g = tid >> 5;
    float gacc[8] = {};
    float facc[8];
#pragma unroll
    for (int i = 0; i < 8; ++i) facc[i] = bs[f];
    for (int c = 0; c < CIN; ++c) {
        float w0 = W0s[c * FF + f], w1 = W1s[c * FF + f];
#pragma unroll
        for (int i = 0; i < 8; ++i) {
            float hv = rows[g + 8 * i][c];
            gacc[i] = fmaf(hv, w1, gacc[i]);
            facc[i] = fmaf(hv, w0, facc[i]);
        }
    }
#pragma unroll
    for (int i = 0; i < 8; ++i) {
        size_t o = (size_t)(r0 + g + 8 * i) * FF + f;
        G[o] = gacc[i];
        F0[o] = facc[i];
    }
}

// ---------------- big GEMM: H = [relu](Lhat @ G + F0) ----------------
// 64x32 tile, thread 4x2, grid (2048/32=64, 512/64=8) = 512 blocks.
// K=512 in steps of 32, single-barrier double-buffered LDS.
template<bool RELU>
__global__ __launch_bounds__(256) void k_prop(
        const float* __restrict__ L, const float* __restrict__ G,
        const float* __restrict__ F0, float* __restrict__ H) {
    __shared__ float As[2][32][65];   // As[buf][k][i]  (i = row in tile)
    __shared__ float Bs[2][32][36];   // Bs[buf][k][j]
    const int tid = threadIdx.x;
    const int tx = tid & 15, ty = tid >> 4;
    const int i0 = blockIdx.y * 64, j0 = blockIdx.x * 32;
    const int arow = tid >> 3;          // 0..31
    const int akc  = (tid & 7) * 4;     // 0,4,...,28
    float acc[4][2] = {};

    float4 pa0, pa1, pb;
    // prologue: load k-tile 0, write buf 0
    pa0 = *(const float4*)&L[(size_t)(i0 + arow) * NN + akc];
    pa1 = *(const float4*)&L[(size_t)(i0 + 32 + arow) * NN + akc];
    pb  = *(const float4*)&G[(size_t)arow * NB + j0 + akc];
    As[0][akc + 0][arow] = pa0.x; As[0][akc + 1][arow] = pa0.y;
    As[0][akc + 2][arow] = pa0.z; As[0][akc + 3][arow] = pa0.w;
    As[0][akc + 0][32 + arow] = pa1.x; As[0][akc + 1][32 + arow] = pa1.y;
    As[0][akc + 2][32 + arow] = pa1.z; As[0][akc + 3][32 + arow] = pa1.w;
    *(float4*)&Bs[0][arow][akc] = pb;
    __syncthreads();

    for (int t = 0; t < 16; ++t) {
        const int buf = t & 1;
        if (t < 15) {   // issue next-tile loads early; latency hides under compute
            const int k0 = (t + 1) * 32;
            pa0 = *(const float4*)&L[(size_t)(i0 + arow) * NN + k0 + akc];
            pa1 = *(const float4*)&L[(size_t)(i0 + 32 + arow) * NN + k0 + akc];
            pb  = *(const float4*)&G[(size_t)(k0 + arow) * NB + j0 + akc];
        }
#pragma unroll
        for (int k = 0; k < 32; ++k) {
            float a[4];
            *(float4*)a = *(const float4*)&As[buf][k][ty * 4];
            float2 b2 = *(const float2*)&Bs[buf][k][tx * 2];
#pragma unroll
            for (int m = 0; m < 4; ++m) {
                acc[m][0] = fmaf(a[m], b2.x, acc[m][0]);
                acc[m][1] = fmaf(a[m], b2.y, acc[m][1]);
            }
        }
        if (t < 15) {
            const int nb = buf ^ 1;
            As[nb][akc + 0][arow] = pa0.x; As[nb][akc + 1][arow] = pa0.y;
            As[nb][akc + 2][arow] = pa0.z; As[nb][akc + 3][arow] = pa0.w;
            As[nb][akc + 0][32 + arow] = pa1.x; As[nb][akc + 1][32 + arow] = pa1.y;
            As[nb][akc + 2][32 + arow] = pa1.z; As[nb][akc + 3][32 + arow] = pa1.w;
            *(float4*)&Bs[nb][arow][akc] = pb;
        }
        __syncthreads();
    }
#pragma unroll
    for (int m = 0; m < 4; ++m) {
        size_t row = i0 + ty * 4 + m;
        float2 f0 = *(const float2*)&F0[row * NB + j0 + tx * 2];
        float2 o;
        o.x = acc[m][0] + f0.x;
        o.y = acc[m][1] + f0.y;
        if (RELU) { o.x = fmaxf(o.x, 0.f); o.y = fmaxf(o.y, 0.f); }
        *(float2*)&H[row * NB + j0 + tx * 2] = o;
    }
}

// ---------------- FC1: out = A(64x16384) @ W(16384x256), K-split partials ----
// grid (8 col-groups of 32, 128 K-chunks of 128). Block 256 = 32 j x 8 bq.
// A[b][k], k = n*32+f  ->  h[n][b][f]; chunk = 4 nodes = 8192 contiguous floats.
// Writes P[kc][b][j] partials (no atomics); reduced in k_fc23.
__global__ __launch_bounds__(256) void k_fc1(const float* __restrict__ h,
                                             const float* __restrict__ W,
                                             float* __restrict__ P) {
    __shared__ float AT[128][68];      // AT[k][b]
    const int tid = threadIdx.x;
    const int jg = blockIdx.x;         // 0..7
    const int kc = blockIdx.y;         // 0..127
    const float* hs = h + (size_t)kc * 4 * NB;
#pragma unroll
    for (int i = 0; i < 8; ++i) {
        int q = tid + i * 256;         // float4 index, 0..2047
        float4 v = *(const float4*)&hs[q * 4];
        int flat = q * 4;
        int nn = flat >> 11, rem = flat & 2047;
        int b = rem >> 5, f0 = rem & 31;
        int krow = nn * 32 + f0;
        AT[krow + 0][b] = v.x; AT[krow + 1][b] = v.y;
        AT[krow + 2][b] = v.z; AT[krow + 3][b] = v.w;
    }
    __syncthreads();
    const int tj = tid & 31, bq = tid >> 5;
    float acc[8] = {};
    const float* wp = W + (size_t)(kc * 128) * 256 + jg * 32 + tj;
#pragma unroll 8
    for (int k = 0; k < 128; ++k) {
        float w = wp[(size_t)k * 256];
        const float* ap = &AT[k][bq * 8];
        float4 a0 = *(const float4*)ap;
        float4 a1 = *(const float4*)(ap + 4);
        acc[0] = fmaf(a0.x, w, acc[0]); acc[1] = fmaf(a0.y, w, acc[1]);
        acc[2] = fmaf(a0.z, w, acc[2]); acc[3] = fmaf(a0.w, w, acc[3]);
        acc[4] = fmaf(a1.x, w, acc[4]); acc[5] = fmaf(a1.y, w, acc[5]);
        acc[6] = fmaf(a1.z, w, acc[6]); acc[7] = fmaf(a1.w, w, acc[7]);
    }
#pragma unroll
    for (int b2 = 0; b2 < 8; ++b2)
        P[(size_t)kc * 16384 + (bq * 8 + b2) * 256 + jg * 32 + tj] = acc[b2];
}

// ---------------- fused reduce + FC2 + FC3 ----------------
// grid 64 (batch); block 128. Reduces fc1 partials, folds fc1 bias.
__global__ __launch_bounds__(128) void k_fc23(const float* __restrict__ P,
        const float* __restrict__ b1, const float* __restrict__ W2,
        const float* __restrict__ b2, const float* __restrict__ W3,
        const float* __restrict__ b3, float* __restrict__ out) {
    __shared__ float row[256];
    __shared__ float r2[128];
    const int m = blockIdx.x, j = threadIdx.x;
#pragma unroll
    for (int rep = 0; rep < 2; ++rep) {
        int k2 = j + rep * 128;
        float s = b1[k2];
#pragma unroll 8
        for (int kc = 0; kc < 128; ++kc)
            s += P[(size_t)kc * 16384 + m * 256 + k2];
        row[k2] = s;
    }
    __syncthreads();
    float acc = b2[j];
#pragma unroll 4
    for (int k = 0; k < 256; ++k)
        acc = fmaf(row[k], W2[k * 128 + j], acc);
    r2[j] = acc;
    __syncthreads();
    const int w = j >> 6, l = j & 63;
    float s2 = r2[l] * W3[l * 2 + w] + r2[l + 64] * W3[(l + 64) * 2 + w];
#pragma unroll
    for (int off = 32; off > 0; off >>= 1)
        s2 += __shfl_down(s2, off);
    if (l == 0) out[m * 2 + w] = s2 + b3[w];
}

// ---------------- launch ----------------

extern "C" void kernel_launch(void* const* d_in, const int* in_sizes, int n_in,
                              void* d_out, int out_size, void* d_ws, size_t ws_size,
                              hipStream_t stream) {
    float* outp = (float*)d_out;
    if (ws_size < (size_t)WS_FLOATS * sizeof(float)) {
        k_zero_out<<<(out_size + 255) / 256, 256, 0, stream>>>(outp, out_size);
        return;
    }

    const float* x  = (const float*)d_in[0];
    const int*   ei = (const int*)d_in[1];
    const float* ew = (const float*)d_in[2];
    const float* cW[6] = {(const float*)d_in[3], (const float*)d_in[5],
                          (const float*)d_in[7], (const float*)d_in[9],
                          (const float*)d_in[11], (const float*)d_in[13]};
    const float* cb[6] = {(const float*)d_in[4], (const float*)d_in[6],
                          (const float*)d_in[8], (const float*)d_in[10],
                          (const float*)d_in[12], (const float*)d_in[14]};
    const float* fc1W = (const float*)d_in[15];
    const float* fc1b = (const float*)d_in[16];
    const float* fc2W = (const float*)d_in[17];
    const float* fc2b = (const float*)d_in[18];
    const float* fc3W = (const float*)d_in[19];
    const float* fc3b = (const float*)d_in[20];

    float* ws   = (float*)d_ws;
    float* Lhat = ws + OFF_LHAT;
    float* deg  = ws + OFF_DEG;
    float* H    = ws + OFF_H;
    float* G    = ws + OFF_G;
    float* F0   = ws + OFF_F0;
    float* P    = ws + OFF_G;   // fc1 partials alias G+F0 (8MB, dead then)

    // build dense Lhat
    k_zero_range<<<(OFF_DEG + 512 + 255) / 256, 256, 0, stream>>>(ws, OFF_DEG + 512);
    k_deg<<<EE / 256, 256, 0, stream>>>(ei, ew, deg);
    k_dinv<<<1, 512, 0, stream>>>(deg);
    k_build<<<EE / 256, 256, 0, stream>>>(ei, ew, deg, Lhat);

    dim3 pgrid(64, 8);
    // layer 1 (CIN=50, from x)
    k_small<TT, true ><<<512, 256, 0, stream>>>(x, cW[0], cb[0], G, F0);
    k_prop<true ><<<pgrid, 256, 0, stream>>>(Lhat, G, F0, H);
    // layers 2..5
    k_small<FF, false><<<512, 256, 0, stream>>>(H, cW[1], cb[1], G, F0);
    k_prop<true ><<<pgrid, 256, 0, stream>>>(Lhat, G, F0, H);
    k_small<FF, false><<<512, 256, 0, stream>>>(H, cW[2], cb[2], G, F0);
    k_prop<true ><<<pgrid, 256, 0, stream>>>(Lhat, G, F0, H);
    k_small<FF, false><<<512, 256, 0, stream>>>(H, cW[3], cb[3], G, F0);
    k_prop<true ><<<pgrid, 256, 0, stream>>>(Lhat, G, F0, H);
    k_small<FF, false><<<512, 256, 0, stream>>>(H, cW[4], cb[4], G, F0);
    k_prop<true ><<<pgrid, 256, 0, stream>>>(Lhat, G, F0, H);
    // layer 6 (no relu)
    k_small<FF, false><<<512, 256, 0, stream>>>(H, cW[5], cb[5], G, F0);
    k_prop<false><<<pgrid, 256, 0, stream>>>(Lhat, G, F0, H);

    // FC head
    dim3 fgrid(8, 128);
    k_fc1<<<fgrid, 256, 0, stream>>>(H, fc1W, P);
    k_fc23<<<64, 128, 0, stream>>>(P, fc1b, fc2W, fc2b, fc3W, fc3b, outp);
}